// Round 3
// baseline (513.925 us; speedup 1.0000x reference)
//
#include <hip/hip_runtime.h>
#include <hip/hip_bf16.h>

#define NB 262144   // batch
#define KD 512      // in_dim
#define ED 10000    // embed_dim

typedef __attribute__((ext_vector_type(8))) short s8v;
typedef __attribute__((ext_vector_type(4))) float f4v;

__device__ __forceinline__ short f2bf(float f) {
  union { __hip_bfloat16 h; short s; } u;
  u.h = __float2bfloat16(f);
  return u.s;
}

// ---------------- prep (merged): W pack + embT transpose ----------------
// blocks [0,512): wbf[i] = bf16(concat(Wlv,Wmu)[i])          (256x512)
// blocks [512, 512+313): embT[v][l] = We[l][v] + be[l]       (10000x128)
__global__ void prep_all(const float* __restrict__ Wlv, const float* __restrict__ Wmu,
                         unsigned short* __restrict__ wbf,
                         const float* __restrict__ We, const float* __restrict__ be,
                         float* __restrict__ embT) {
  __shared__ float t[32][129];
  if (blockIdx.x < 512) {
    int i = blockIdx.x * 256 + threadIdx.x;          // [0, 131072)
    int row = i >> 9, col = i & 511;
    float v = (row < 128) ? Wlv[(row << 9) | col] : Wmu[((row - 128) << 9) | col];
    union { __hip_bfloat16 h; unsigned short s; } u;
    u.h = __float2bfloat16(v);
    wbf[i] = u.s;
  } else {
    const int v0 = (blockIdx.x - 512) << 5;
#pragma unroll
    for (int j = 0; j < 16; ++j) {
      int idx = j * 256 + threadIdx.x;               // [0, 4096)
      int l = idx >> 5, vi = idx & 31;
      int v = v0 + vi;
      t[vi][l] = (v < ED) ? We[(size_t)l * ED + v] : 0.f;
    }
    __syncthreads();
#pragma unroll
    for (int j = 0; j < 16; ++j) {
      int idx = j * 256 + threadIdx.x;
      int v = idx >> 7, l = idx & 127;
      if (v0 + v < ED)
        embT[(size_t)(v0 + v) * 128 + l] = t[v][l] + be[l];
    }
  }
}

// ---------------- main: barrier-free streaming GEMM + fused embed ----------------
// Block: 512 threads = 8 waves (wm 0..3 x wn 0..1); block tile 128 rows x 256 cols.
// Wave tile: 32 rows x 128 cols. A direct from x (fp32->bf16), B direct from
// L2-resident wbf. No LDS, no __syncthreads in the GEMM path.
__global__ __launch_bounds__(512, 2) void gemm_heads(
    const float* __restrict__ x, const unsigned short* __restrict__ wbf,
    const float* __restrict__ blv, const float* __restrict__ bmu,
    const int* __restrict__ y, const float* __restrict__ embT,
    float* __restrict__ out, int doEmbed) {
  const int tid  = threadIdx.x;
  const int lane = tid & 63;
  const int wid  = tid >> 6;
  const int wm   = wid >> 1;   // 0..3  (M: 32-row group)
  const int wn   = wid & 1;    // 0..1  (N: 128-col half)
  const int gm   = blockIdx.x << 7;
  const int lr   = lane & 15;  // row-in-tile / col-in-tile
  const int kg   = lane >> 4;  // k-group (8 elems each)

  // A: lane reads x[gm + wm*32 + (m*16) + lr][t*32 + kg*8 .. +8]  (32B fp32)
  const float* pa0 = x + (((size_t)(gm + (wm << 5) + lr)) << 9) + (kg << 3);
  const float* pa1 = pa0 + (16 << 9);
  // B: lane reads wbf[wn*128 + nt*16 + lr][t*32 + kg*8 .. +8]     (16B bf16)
  const unsigned short* pb[8];
#pragma unroll
  for (int nt = 0; nt < 8; ++nt)
    pb[nt] = wbf + (((size_t)((wn << 7) + (nt << 4) + lr)) << 9) + (kg << 3);

  f4v acc[2][8];
#pragma unroll
  for (int m = 0; m < 2; ++m)
#pragma unroll
    for (int nt = 0; nt < 8; ++nt) acc[m][nt] = (f4v)0.f;

  for (int t4 = 0; t4 < 4; ++t4) {
#pragma unroll
    for (int u = 0; u < 4; ++u) {
      const int ko = u << 5;                 // +u*32 elements
      float4 a0lo = *(const float4*)(pa0 + ko);
      float4 a0hi = *(const float4*)(pa0 + ko + 4);
      float4 a1lo = *(const float4*)(pa1 + ko);
      float4 a1hi = *(const float4*)(pa1 + ko + 4);
      s8v af0, af1;
      af0[0] = f2bf(a0lo.x); af0[1] = f2bf(a0lo.y); af0[2] = f2bf(a0lo.z); af0[3] = f2bf(a0lo.w);
      af0[4] = f2bf(a0hi.x); af0[5] = f2bf(a0hi.y); af0[6] = f2bf(a0hi.z); af0[7] = f2bf(a0hi.w);
      af1[0] = f2bf(a1lo.x); af1[1] = f2bf(a1lo.y); af1[2] = f2bf(a1lo.z); af1[3] = f2bf(a1lo.w);
      af1[4] = f2bf(a1hi.x); af1[5] = f2bf(a1hi.y); af1[6] = f2bf(a1hi.z); af1[7] = f2bf(a1hi.w);
#pragma unroll
      for (int nt = 0; nt < 8; ++nt) {
        s8v bf = *(const s8v*)(pb[nt] + ko);
        acc[0][nt] = __builtin_amdgcn_mfma_f32_16x16x32_bf16(af0, bf, acc[0][nt], 0, 0, 0);
        acc[1][nt] = __builtin_amdgcn_mfma_f32_16x16x32_bf16(af1, bf, acc[1][nt], 0, 0, 0);
      }
    }
    pa0 += 128; pa1 += 128;
#pragma unroll
    for (int nt = 0; nt < 8; ++nt) pb[nt] += 128;
  }

  // epilogue: C/D layout col=lane&15, row=(lane>>4)*4+r   (known-good mapping)
  const int rsub = kg << 2;
#pragma unroll
  for (int nt = 0; nt < 8; ++nt) {
    int col = (wn << 7) + (nt << 4) + lr;
    float bias = (col < 128) ? blv[col] : bmu[col - 128];
    float* ob = (col < 128) ? (out + col)
                            : (out + ((size_t)NB << 7) + (col - 128));
#pragma unroll
    for (int m = 0; m < 2; ++m) {
      int row0 = gm + (wm << 5) + (m << 4) + rsub;
#pragma unroll
      for (int r = 0; r < 4; ++r)
        ob[(size_t)(row0 + r) << 7] = acc[m][nt][r] + bias;
    }
  }

  // fused embed: this block's 128 rows; embT is L2-resident
  if (doEmbed) {
    float* out3 = out + ((size_t)NB << 8);
    int r  = tid >> 2;            // 0..127
    int c0 = (tid & 3) << 5;      // 0,32,64,96 (floats)
    int row = gm + r;
    int v = y[row];
    const float4* src = (const float4*)(embT + (size_t)v * 128 + c0);
    float4* dst = (float4*)(out3 + ((size_t)row << 7) + c0);
#pragma unroll
    for (int j = 0; j < 8; ++j) dst[j] = src[j];
  }
}

// ---------------- fallbacks (only if ws_size too small) ----------------
__global__ void gemm_naive(const float* __restrict__ x,
                           const float* __restrict__ Wlv, const float* __restrict__ blv,
                           const float* __restrict__ Wmu, const float* __restrict__ bmu,
                           float* __restrict__ out) {
  __shared__ float xr[512];
  int b = blockIdx.x;
  for (int i = threadIdx.x; i < 512; i += 256) xr[i] = x[(size_t)b * 512 + i];
  __syncthreads();
  int c = threadIdx.x;
  const float* w = (c < 128) ? (Wlv + c * 512) : (Wmu + (c - 128) * 512);
  float s = 0.f;
  for (int k = 0; k < 512; ++k) s += xr[k] * w[k];
  s += (c < 128) ? blv[c] : bmu[c - 128];
  float* o = (c < 128) ? (out + (size_t)b * 128 + c)
                       : (out + ((size_t)NB << 7) + (size_t)b * 128 + (c - 128));
  *o = s;
}

__global__ void embed_direct(const int* __restrict__ y, const float* __restrict__ We,
                             const float* __restrict__ be, float* __restrict__ out3) {
  size_t t = (size_t)blockIdx.x * 256 + threadIdx.x;
  int b = (int)(t >> 7), l = (int)(t & 127);
  out3[t] = We[(size_t)l * ED + y[b]] + be[l];
}

extern "C" void kernel_launch(void* const* d_in, const int* in_sizes, int n_in,
                              void* d_out, int out_size, void* d_ws, size_t ws_size,
                              hipStream_t stream) {
  const float* x   = (const float*)d_in[0];
  const int*   y   = (const int*)d_in[1];
  const float* Wlv = (const float*)d_in[2];
  const float* blv = (const float*)d_in[3];
  const float* Wmu = (const float*)d_in[4];
  const float* bmu = (const float*)d_in[5];
  const float* We  = (const float*)d_in[6];
  const float* be  = (const float*)d_in[7];
  float* out  = (float*)d_out;
  float* out3 = out + ((size_t)NB << 8);

  const size_t needW = 256 * 512 * sizeof(unsigned short);          // 256 KB
  const size_t needE = needW + (size_t)ED * 128 * sizeof(float);    // + 5.12 MB
  unsigned short* wbf = (unsigned short*)d_ws;
  float* embT = (float*)((char*)d_ws + needW);

  if (ws_size >= needE) {
    prep_all<<<512 + 313, 256, 0, stream>>>(Wlv, Wmu, wbf, We, be, embT);
    gemm_heads<<<NB / 128, 512, 0, stream>>>(x, wbf, blv, bmu, y, embT, out, 1);
  } else if (ws_size >= needW) {
    prep_all<<<512, 256, 0, stream>>>(Wlv, Wmu, wbf, We, be, (float*)d_ws); // embT part skipped by grid
    gemm_heads<<<NB / 128, 512, 0, stream>>>(x, wbf, blv, bmu, y, nullptr, out, 0);
    embed_direct<<<NB * 128 / 256, 256, 0, stream>>>(y, We, be, out3);
  } else {
    gemm_naive<<<NB, 256, 0, stream>>>(x, Wlv, blv, Wmu, bmu, out);
    embed_direct<<<NB * 128 / 256, 256, 0, stream>>>(y, We, be, out3);
  }
}

// Round 4
// 386.448 us; speedup vs baseline: 1.3299x; 1.3299x over previous
//
#include <hip/hip_runtime.h>
#include <hip/hip_bf16.h>

#define NB 262144   // batch
#define KD 512      // in_dim
#define ED 10000    // embed_dim

typedef __attribute__((ext_vector_type(8))) short s8v;
typedef __attribute__((ext_vector_type(4))) float f4v;

typedef __attribute__((address_space(1))) const unsigned int gu32_t;
typedef __attribute__((address_space(3))) unsigned int lu32_t;

__device__ __forceinline__ short f2bf(float f) {
  union { __hip_bfloat16 h; short s; } u;
  u.h = __float2bfloat16(f);
  return u.s;
}

// ---------------- prep (merged): W pack + embT transpose ----------------
__global__ void prep_all(const float* __restrict__ Wlv, const float* __restrict__ Wmu,
                         unsigned short* __restrict__ wbf,
                         const float* __restrict__ We, const float* __restrict__ be,
                         float* __restrict__ embT) {
  __shared__ float t[32][129];
  if (blockIdx.x < 512) {
    int i = blockIdx.x * 256 + threadIdx.x;          // [0, 131072)
    int row = i >> 9, col = i & 511;
    float v = (row < 128) ? Wlv[(row << 9) | col] : Wmu[((row - 128) << 9) | col];
    union { __hip_bfloat16 h; unsigned short s; } u;
    u.h = __float2bfloat16(v);
    wbf[i] = u.s;
  } else {
    const int v0 = (blockIdx.x - 512) << 5;
#pragma unroll
    for (int j = 0; j < 16; ++j) {
      int idx = j * 256 + threadIdx.x;               // [0, 4096)
      int l = idx >> 5, vi = idx & 31;
      int v = v0 + vi;
      t[vi][l] = (v < ED) ? We[(size_t)l * ED + v] : 0.f;
    }
    __syncthreads();
#pragma unroll
    for (int j = 0; j < 16; ++j) {
      int idx = j * 256 + threadIdx.x;
      int v = idx >> 7, l = idx & 127;
      if (v0 + v < ED)
        embT[(size_t)(v0 + v) * 128 + l] = t[v][l] + be[l];
    }
  }
}

// ---------------- main GEMM: 4-stage gl_lds pipeline, counted vmcnt ----------------
// BM=64, BN=256, BK=64, 8 tiles. A fp32 staged in LDS [4 stages][64][64] (swizzled),
// B bf16 direct from L2-resident wbf. 8 waves: wm 0..1 (32-row), wn 0..3 (64-col).
__global__ __launch_bounds__(512, 4) void gemm_heads(
    const float* __restrict__ x, const unsigned short* __restrict__ wbf,
    const float* __restrict__ blv, const float* __restrict__ bmu,
    const int* __restrict__ y, const float* __restrict__ embT,
    float* __restrict__ out, int doEmbed) {
  __shared__ float lds[4 * 4096];                    // 64 KB
  char* ldsc = (char*)lds;
  const int tid  = threadIdx.x;
  const int lane = tid & 63;
  const int wid  = tid >> 6;
  const int wm   = wid >> 2;   // 0..1
  const int wn   = wid & 3;    // 0..3
  const int gm   = blockIdx.x << 6;
  const int lr   = lane & 15;
  const int kg   = lane >> 4;

  // staging: 2 chunks/thread/stage; chunk c: row=c>>4 (16 chunks per 256B row),
  // q=c&15, source pre-swizzled q'=q^(row&7); LDS dest linear (rule 21).
  unsigned aSrc[2], aDstC[2];
#pragma unroll
  for (int s = 0; s < 2; ++s) {
    int c = tid + (s << 9);
    int row = c >> 4, q = c & 15;
    int qp = q ^ (row & 7);
    aSrc[s]  = (unsigned)(row << 9) + (unsigned)(qp << 2);  // float elements (+ke)
    aDstC[s] = (unsigned)(c << 4);                          // bytes within stage
  }
  const float* xblk = x + ((size_t)gm << 9);

  // B base pointers: 4 (tile offsets fold into 13-bit imm)
  const unsigned short* pb[4];
#pragma unroll
  for (int nt = 0; nt < 4; ++nt)
    pb[nt] = wbf + (((size_t)((wn << 6) + (nt << 4) + lr)) << 9) + (kg << 3);

  f4v acc[2][4];
#pragma unroll
  for (int m = 0; m < 2; ++m)
#pragma unroll
    for (int nt = 0; nt < 4; ++nt) acc[m][nt] = (f4v)0.f;

  // prologue: stage tiles 0,1,2
#pragma unroll
  for (int st = 0; st < 3; ++st) {
    const int ke = st << 6;
    const unsigned sb = (unsigned)(st << 14);
#pragma unroll
    for (int s = 0; s < 2; ++s)
      __builtin_amdgcn_global_load_lds((const gu32_t*)(xblk + aSrc[s] + ke),
                                       (lu32_t*)(ldsc + sb + aDstC[s]), 16, 0, 0);
  }
  asm volatile("s_waitcnt vmcnt(4)" ::: "memory");   // tile 0 landed (own wave)
  __builtin_amdgcn_s_barrier();                       // all waves' tile 0 landed

#pragma unroll
  for (int t = 0; t < 8; ++t) {
    const float* ldsA = lds + ((t & 3) << 12);
    // B for this tile: 2 k-steps x 4 frags (issued BEFORE next gl -> waits on B
    // never drain the ahead-stream beyond g_{t+2})
    s8v bfr[2][4];
#pragma unroll
    for (int ks = 0; ks < 2; ++ks)
#pragma unroll
      for (int nt = 0; nt < 4; ++nt)
        bfr[ks][nt] = *(const s8v*)(pb[nt] + (t << 6) + (ks << 5));
    // prefetch stage t+3 (writes buffer freed by iter t-1's barrier)
    if (t <= 4) {
      const int ke = (t + 3) << 6;
      const unsigned sb = (unsigned)(((t + 3) & 3) << 14);
#pragma unroll
      for (int s = 0; s < 2; ++s)
        __builtin_amdgcn_global_load_lds((const gu32_t*)(xblk + aSrc[s] + ke),
                                         (lu32_t*)(ldsc + sb + aDstC[s]), 16, 0, 0);
    }
    // compute tile t
#pragma unroll
    for (int ks = 0; ks < 2; ++ks) {
      s8v af[2];
#pragma unroll
      for (int m = 0; m < 2; ++m) {
        const int row = (wm << 5) + (m << 4) + lr;
        const int u0 = (ks << 3) + (kg << 1);
        const int sw = lr & 7;
        float4 a0 = *(const float4*)(ldsA + (row << 6) + (((u0)     ^ sw) << 2));
        float4 a1 = *(const float4*)(ldsA + (row << 6) + (((u0 + 1) ^ sw) << 2));
        af[m][0] = f2bf(a0.x); af[m][1] = f2bf(a0.y); af[m][2] = f2bf(a0.z); af[m][3] = f2bf(a0.w);
        af[m][4] = f2bf(a1.x); af[m][5] = f2bf(a1.y); af[m][6] = f2bf(a1.z); af[m][7] = f2bf(a1.w);
      }
#pragma unroll
      for (int m = 0; m < 2; ++m)
#pragma unroll
        for (int nt = 0; nt < 4; ++nt)
          acc[m][nt] = __builtin_amdgcn_mfma_f32_16x16x32_bf16(af[m], bfr[ks][nt], acc[m][nt], 0, 0, 0);
    }
    // end of iter: keep g_{t+3} in flight; ensure LDS reads retired, then barrier
    asm volatile("s_waitcnt lgkmcnt(0)" ::: "memory");
    __builtin_amdgcn_sched_barrier(0);
    if (t <= 4) { asm volatile("s_waitcnt vmcnt(2)" ::: "memory"); }
    else        { asm volatile("s_waitcnt vmcnt(0)" ::: "memory"); }
    __builtin_amdgcn_s_barrier();
  }

  // epilogue: C/D layout col=lane&15, row=(lane>>4)*4+r (validated r1/r3)
  const int rsub = kg << 2;
#pragma unroll
  for (int nt = 0; nt < 4; ++nt) {
    int col = (wn << 6) + (nt << 4) + lr;
    float bias = (col < 128) ? blv[col] : bmu[col - 128];
    float* ob = (col < 128) ? (out + col)
                            : (out + ((size_t)NB << 7) + (col - 128));
#pragma unroll
    for (int m = 0; m < 2; ++m) {
      int row0 = gm + (wm << 5) + (m << 4) + rsub;
#pragma unroll
      for (int r = 0; r < 4; ++r)
        ob[(size_t)(row0 + r) << 7] = acc[m][nt][r] + bias;
    }
  }

  // fused embed: this block's 64 rows; embT is L2-resident
  if (doEmbed) {
    float* out3 = out + ((size_t)NB << 8);
    int r  = tid >> 3;            // 0..63
    int c0 = (tid & 7) << 4;      // 0,16,...,112 (floats)
    int row = gm + r;
    int v = y[row];
    const float4* src = (const float4*)(embT + (size_t)v * 128 + c0);
    float4* dst = (float4*)(out3 + ((size_t)row << 7) + c0);
#pragma unroll
    for (int j = 0; j < 4; ++j) dst[j] = src[j];
  }
}

// ---------------- fallbacks (only if ws_size too small) ----------------
__global__ void gemm_naive(const float* __restrict__ x,
                           const float* __restrict__ Wlv, const float* __restrict__ blv,
                           const float* __restrict__ Wmu, const float* __restrict__ bmu,
                           float* __restrict__ out) {
  __shared__ float xr[512];
  int b = blockIdx.x;
  for (int i = threadIdx.x; i < 512; i += 256) xr[i] = x[(size_t)b * 512 + i];
  __syncthreads();
  int c = threadIdx.x;
  const float* w = (c < 128) ? (Wlv + c * 512) : (Wmu + (c - 128) * 512);
  float s = 0.f;
  for (int k = 0; k < 512; ++k) s += xr[k] * w[k];
  s += (c < 128) ? blv[c] : bmu[c - 128];
  float* o = (c < 128) ? (out + (size_t)b * 128 + c)
                       : (out + ((size_t)NB << 7) + (size_t)b * 128 + (c - 128));
  *o = s;
}

__global__ void embed_direct(const int* __restrict__ y, const float* __restrict__ We,
                             const float* __restrict__ be, float* __restrict__ out3) {
  size_t t = (size_t)blockIdx.x * 256 + threadIdx.x;
  int b = (int)(t >> 7), l = (int)(t & 127);
  out3[t] = We[(size_t)l * ED + y[b]] + be[l];
}

extern "C" void kernel_launch(void* const* d_in, const int* in_sizes, int n_in,
                              void* d_out, int out_size, void* d_ws, size_t ws_size,
                              hipStream_t stream) {
  const float* x   = (const float*)d_in[0];
  const int*   y   = (const int*)d_in[1];
  const float* Wlv = (const float*)d_in[2];
  const float* blv = (const float*)d_in[3];
  const float* Wmu = (const float*)d_in[4];
  const float* bmu = (const float*)d_in[5];
  const float* We  = (const float*)d_in[6];
  const float* be  = (const float*)d_in[7];
  float* out  = (float*)d_out;
  float* out3 = out + ((size_t)NB << 8);

  const size_t needW = 256 * 512 * sizeof(unsigned short);          // 256 KB
  const size_t needE = needW + (size_t)ED * 128 * sizeof(float);    // + 5.12 MB
  unsigned short* wbf = (unsigned short*)d_ws;
  float* embT = (float*)((char*)d_ws + needW);

  if (ws_size >= needE) {
    prep_all<<<512 + 313, 256, 0, stream>>>(Wlv, Wmu, wbf, We, be, embT);
    gemm_heads<<<NB / 64, 512, 0, stream>>>(x, wbf, blv, bmu, y, embT, out, 1);
  } else if (ws_size >= needW) {
    prep_all<<<512, 256, 0, stream>>>(Wlv, Wmu, wbf, We, be, (float*)d_ws);
    gemm_heads<<<NB / 64, 512, 0, stream>>>(x, wbf, blv, bmu, y, nullptr, out, 0);
    embed_direct<<<NB * 128 / 256, 256, 0, stream>>>(y, We, be, out3);
  } else {
    gemm_naive<<<NB, 256, 0, stream>>>(x, Wlv, blv, Wmu, bmu, out);
    embed_direct<<<NB * 128 / 256, 256, 0, stream>>>(y, We, be, out3);
  }
}

// Round 5
// 296.892 us; speedup vs baseline: 1.7310x; 1.3016x over previous
//
#include <hip/hip_runtime.h>
#include <hip/hip_bf16.h>

#define NB 262144   // batch
#define KD 512      // in_dim
#define ED 10000    // embed_dim

typedef __attribute__((ext_vector_type(8))) short s8v;
typedef __attribute__((ext_vector_type(4))) float f4v;

typedef __attribute__((address_space(1))) const unsigned int gu32_t;
typedef __attribute__((address_space(3))) unsigned int lu32_t;

__device__ __forceinline__ short f2bf(float f) {
  union { __hip_bfloat16 h; short s; } u;
  u.h = __float2bfloat16(f);
  return u.s;
}

// ---------------- prep (merged): W pack + embT transpose ----------------
__global__ void prep_all(const float* __restrict__ Wlv, const float* __restrict__ Wmu,
                         unsigned short* __restrict__ wbf,
                         const float* __restrict__ We, const float* __restrict__ be,
                         float* __restrict__ embT) {
  __shared__ float t[32][129];
  if (blockIdx.x < 512) {
    int i = blockIdx.x * 256 + threadIdx.x;          // [0, 131072)
    int row = i >> 9, col = i & 511;
    float v = (row < 128) ? Wlv[(row << 9) | col] : Wmu[((row - 128) << 9) | col];
    union { __hip_bfloat16 h; unsigned short s; } u;
    u.h = __float2bfloat16(v);
    wbf[i] = u.s;
  } else {
    const int v0 = (blockIdx.x - 512) << 5;
#pragma unroll
    for (int j = 0; j < 16; ++j) {
      int idx = j * 256 + threadIdx.x;               // [0, 4096)
      int l = idx >> 5, vi = idx & 31;
      int v = v0 + vi;
      t[vi][l] = (v < ED) ? We[(size_t)l * ED + v] : 0.f;
    }
    __syncthreads();
#pragma unroll
    for (int j = 0; j < 16; ++j) {
      int idx = j * 256 + threadIdx.x;
      int v = idx >> 7, l = idx & 127;
      if (v0 + v < ED)
        embT[(size_t)(v0 + v) * 128 + l] = t[v][l] + be[l];
    }
  }
}

// ---------------- main GEMM: homogeneous gl_lds stream, counted vmcnt ----------------
// BM=64, BN=256, BK=32, 16 tiles. Stage (24KB) = A fp32 [64][32] (8KB, swz) +
// B bf16 [256][32] (16KB, swz). 3 stages = 72KB -> 2 blocks/CU.
// 8 waves: wm 0..1 (32 rows), wn 0..3 (64 cols); wave tile 32x64; acc 32 VGPR.
__global__ __launch_bounds__(512, 4) void gemm_heads(
    const float* __restrict__ x, const unsigned short* __restrict__ wbf,
    const float* __restrict__ blv, const float* __restrict__ bmu,
    const int* __restrict__ y, const float* __restrict__ embT,
    float* __restrict__ out, int doEmbed) {
  __shared__ char lds[3 * 24576];                    // 72 KB
  const int tid  = threadIdx.x;
  const int lane = tid & 63;
  const int wid  = tid >> 6;
  const int wm   = wid >> 2;   // 0..1
  const int wn   = wid & 3;    // 0..3
  const int gm   = blockIdx.x << 6;
  const int lr   = lane & 15;
  const int kg   = lane >> 4;

  // --- staging descriptors (rule 21: linear LDS dest, pre-swizzled source) ---
  // A: 512 chunks; chunk c=tid: row=c>>3 (8 chunks per 128B row), q=c&7, src q^=(row&7)
  const int arow = tid >> 3, aq = tid & 7;
  const unsigned aSrcBase = (unsigned)(arow << 9) + (unsigned)((aq ^ (arow & 7)) << 2); // fp32 elems
  const unsigned aDst = (unsigned)(tid << 4);
  // B: 1024 chunks; chunk c: col=c>>2 (4 chunks per 64B row), q=c&3, src q^=((col>>1)&3)
  unsigned bSrcBase[2], bDst[2];
#pragma unroll
  for (int s = 0; s < 2; ++s) {
    int c = tid + (s << 9);
    int col = c >> 2, q = c & 3;
    int qp = q ^ ((col >> 1) & 3);
    bSrcBase[s] = (unsigned)(col << 9) + (unsigned)(qp << 3);   // bf16 elems
    bDst[s] = 8192u + (unsigned)(c << 4);
  }
  const float* xblk = x + ((size_t)gm << 9);

  // --- fragment-read byte offsets within a stage ---
  unsigned offA[2][2], offB[4];
#pragma unroll
  for (int m = 0; m < 2; ++m) {
    int row = (wm << 5) + (m << 4) + lr;
    int sw = row & 7;
    offA[m][0] = (unsigned)(row << 7) + (unsigned)((((kg << 1))     ^ sw) << 4);
    offA[m][1] = (unsigned)(row << 7) + (unsigned)((((kg << 1) + 1) ^ sw) << 4);
  }
#pragma unroll
  for (int nt = 0; nt < 4; ++nt) {
    int col = (wn << 6) + (nt << 4) + lr;
    offB[nt] = 8192u + (unsigned)(col << 6) + (unsigned)((kg ^ ((col >> 1) & 3)) << 4);
  }

  f4v acc[2][4];
#pragma unroll
  for (int m = 0; m < 2; ++m)
#pragma unroll
    for (int nt = 0; nt < 4; ++nt) acc[m][nt] = (f4v)0.f;

#define ISSUE_STAGE(st)                                                            \
  {                                                                                \
    const int ke = (st) << 5;                                                      \
    char* sb = lds + ((st) % 3) * 24576;                                           \
    __builtin_amdgcn_global_load_lds((const gu32_t*)(xblk + aSrcBase + ke),        \
                                     (lu32_t*)(sb + aDst), 16, 0, 0);              \
    __builtin_amdgcn_global_load_lds((const gu32_t*)(wbf + bSrcBase[0] + ke),      \
                                     (lu32_t*)(sb + bDst[0]), 16, 0, 0);           \
    __builtin_amdgcn_global_load_lds((const gu32_t*)(wbf + bSrcBase[1] + ke),      \
                                     (lu32_t*)(sb + bDst[1]), 16, 0, 0);           \
  }

  // prologue: stages 0,1 in flight; wait stage 0 (own ops), sync
  ISSUE_STAGE(0)
  ISSUE_STAGE(1)
  asm volatile("s_waitcnt vmcnt(3)" ::: "memory");
  __builtin_amdgcn_s_barrier();

#pragma unroll
  for (int t = 0; t < 16; ++t) {
    // issue stage t+2 into buf (t+2)%3 (its previous reads completed before the
    // last barrier — lgkmcnt(0) below guarantees that)
    if (t <= 13) ISSUE_STAGE(t + 2)
    const char* stage = lds + (t % 3) * 24576;
    // fragments for tile t
    s8v bfr[4];
#pragma unroll
    for (int nt = 0; nt < 4; ++nt)
      bfr[nt] = *(const s8v*)(stage + offB[nt]);
    s8v af[2];
#pragma unroll
    for (int m = 0; m < 2; ++m) {
      float4 a0 = *(const float4*)(stage + offA[m][0]);
      float4 a1 = *(const float4*)(stage + offA[m][1]);
      af[m][0] = f2bf(a0.x); af[m][1] = f2bf(a0.y); af[m][2] = f2bf(a0.z); af[m][3] = f2bf(a0.w);
      af[m][4] = f2bf(a1.x); af[m][5] = f2bf(a1.y); af[m][6] = f2bf(a1.z); af[m][7] = f2bf(a1.w);
    }
#pragma unroll
    for (int m = 0; m < 2; ++m)
#pragma unroll
      for (int nt = 0; nt < 4; ++nt)
        acc[m][nt] = __builtin_amdgcn_mfma_f32_16x16x32_bf16(af[m], bfr[nt], acc[m][nt], 0, 0, 0);
    // retire my LDS reads (so post-barrier overwrites of this buf are safe)
    asm volatile("s_waitcnt lgkmcnt(0)" ::: "memory");
    __builtin_amdgcn_sched_barrier(0);
    // counted vmcnt: stage t+1 landed, stage t+2 stays in flight
    if (t <= 13)      { asm volatile("s_waitcnt vmcnt(3)" ::: "memory"); }
    else if (t == 14) { asm volatile("s_waitcnt vmcnt(0)" ::: "memory"); }
    if (t <= 14) __builtin_amdgcn_s_barrier();
  }
#undef ISSUE_STAGE

  // epilogue: C/D layout col=lane&15, row=(lane>>4)*4+r (validated r1/r4)
  const int rsub = kg << 2;
#pragma unroll
  for (int nt = 0; nt < 4; ++nt) {
    int col = (wn << 6) + (nt << 4) + lr;
    float bias = (col < 128) ? blv[col] : bmu[col - 128];
    float* ob = (col < 128) ? (out + col)
                            : (out + ((size_t)NB << 7) + (col - 128));
#pragma unroll
    for (int m = 0; m < 2; ++m) {
      int row0 = gm + (wm << 5) + (m << 4) + rsub;
#pragma unroll
      for (int r = 0; r < 4; ++r)
        ob[(size_t)(row0 + r) << 7] = acc[m][nt][r] + bias;
    }
  }

  // fused embed: this block's 64 rows; embT is L2-resident
  if (doEmbed) {
    float* out3 = out + ((size_t)NB << 8);
    int r  = tid >> 3;            // 0..63
    int c0 = (tid & 7) << 4;      // 0..112 (floats)
    int row = gm + r;
    int v = y[row];
    const float4* src = (const float4*)(embT + (size_t)v * 128 + c0);
    float4* dst = (float4*)(out + ((size_t)NB << 8) - ((size_t)NB << 8) + ((size_t)row << 7) + c0 + ((size_t)NB << 8) - ((size_t)row << 7) - c0 + ((size_t)row << 7) + c0);
    dst = (float4*)(out3 + ((size_t)row << 7) + c0);
#pragma unroll
    for (int j = 0; j < 4; ++j) dst[j] = src[j];
  }
}

// ---------------- fallbacks (only if ws_size too small) ----------------
__global__ void gemm_naive(const float* __restrict__ x,
                           const float* __restrict__ Wlv, const float* __restrict__ blv,
                           const float* __restrict__ Wmu, const float* __restrict__ bmu,
                           float* __restrict__ out) {
  __shared__ float xr[512];
  int b = blockIdx.x;
  for (int i = threadIdx.x; i < 512; i += 256) xr[i] = x[(size_t)b * 512 + i];
  __syncthreads();
  int c = threadIdx.x;
  const float* w = (c < 128) ? (Wlv + c * 512) : (Wmu + (c - 128) * 512);
  float s = 0.f;
  for (int k = 0; k < 512; ++k) s += xr[k] * w[k];
  s += (c < 128) ? blv[c] : bmu[c - 128];
  float* o = (c < 128) ? (out + (size_t)b * 128 + c)
                       : (out + ((size_t)NB << 7) + (size_t)b * 128 + (c - 128));
  *o = s;
}

__global__ void embed_direct(const int* __restrict__ y, const float* __restrict__ We,
                             const float* __restrict__ be, float* __restrict__ out3) {
  size_t t = (size_t)blockIdx.x * 256 + threadIdx.x;
  int b = (int)(t >> 7), l = (int)(t & 127);
  out3[t] = We[(size_t)l * ED + y[b]] + be[l];
}

extern "C" void kernel_launch(void* const* d_in, const int* in_sizes, int n_in,
                              void* d_out, int out_size, void* d_ws, size_t ws_size,
                              hipStream_t stream) {
  const float* x   = (const float*)d_in[0];
  const int*   y   = (const int*)d_in[1];
  const float* Wlv = (const float*)d_in[2];
  const float* blv = (const float*)d_in[3];
  const float* Wmu = (const float*)d_in[4];
  const float* bmu = (const float*)d_in[5];
  const float* We  = (const float*)d_in[6];
  const float* be  = (const float*)d_in[7];
  float* out  = (float*)d_out;
  float* out3 = out + ((size_t)NB << 8);

  const size_t needW = 256 * 512 * sizeof(unsigned short);          // 256 KB
  const size_t needE = needW + (size_t)ED * 128 * sizeof(float);    // + 5.12 MB
  unsigned short* wbf = (unsigned short*)d_ws;
  float* embT = (float*)((char*)d_ws + needW);

  if (ws_size >= needE) {
    prep_all<<<512 + 313, 256, 0, stream>>>(Wlv, Wmu, wbf, We, be, embT);
    gemm_heads<<<NB / 64, 512, 0, stream>>>(x, wbf, blv, bmu, y, embT, out, 1);
  } else if (ws_size >= needW) {
    prep_all<<<512, 256, 0, stream>>>(Wlv, Wmu, wbf, We, be, (float*)d_ws);
    gemm_heads<<<NB / 64, 512, 0, stream>>>(x, wbf, blv, bmu, y, nullptr, out, 0);
    embed_direct<<<NB * 128 / 256, 256, 0, stream>>>(y, We, be, out3);
  } else {
    gemm_naive<<<NB, 256, 0, stream>>>(x, Wlv, blv, Wmu, bmu, out);
    embed_direct<<<NB * 128 / 256, 256, 0, stream>>>(y, We, be, out3);
  }
}